// Round 9
// baseline (19378.380 us; speedup 1.0000x reference)
//
#include <hip/hip_runtime.h>
#include <hip/hip_bf16.h>

// EncoderDecoderConvLSTM — Round 9: FLOAT32 OUTPUT (the round-2..8 failure was
// writing bf16 into a float32 d_out: y region aliased to bf16 pairs ≈ y[2i+1],
// and the encoder-vector region bled into output 0's float range, giving the
// bit-stable 0.2488 = max|h_enc|. Probes written as bf16 out[0] only touched
// the low mantissa bits of float_out[0] — structurally invisible.)
// Inputs f32 (proven: round-1 bf16 misread -> NaN). States f32 in ws.
// Decoder trick: steps t>=1 have comb=[h,h] -> conv with (Wx+Wh) summed, 64ch.

#define HW 4096
#define NF 64

__device__ __forceinline__ float fsig(float v) {
  return __builtin_amdgcn_rcpf(1.f + __expf(-v));
}
__device__ __forceinline__ float ftanh(float v) {
  float vc = fminf(fmaxf(v, -15.f), 15.f);
  float e = __expf(2.f * vc);
  return (e - 1.f) * __builtin_amdgcn_rcpf(e + 1.f);
}

// accumulate one input channel (3x3) into 8 features x 4 gates
__device__ __forceinline__ void accum_channel(const float* __restrict__ plane,
                                              const int off[9], const bool val[9],
                                              const float* __restrict__ w288,
                                              float acc[8][4]) {
  float n[9];
#pragma unroll
  for (int k = 0; k < 9; ++k) n[k] = val[k] ? plane[off[k]] : 0.f;
#pragma unroll
  for (int j = 0; j < 8; ++j) {
#pragma unroll
    for (int g = 0; g < 4; ++g) {
      const float* wp = w288 + (j * 4 + g) * 9;
      float a = acc[j][g];
#pragma unroll
      for (int k = 0; k < 9; ++k) a = fmaf(wp[k], n[k], a);
      acc[j][g] = a;
    }
  }
}

// Fused ConvLSTM step: conv(comb) + gates + state update.
// Weights reordered as [c][ftile(8)][j(8)*4+g][9] contiguous 288-float chunks.
// bias is the NATIVE 256-float array indexed by oc = g*64 + ft*8 + j.
template <int E, bool SKIP_H>
__global__ __launch_bounds__(256) void lstm_step_k(
    const float* __restrict__ ext, int extBS,
    const float* __restrict__ Wext, const float* __restrict__ Wh,
    const float* __restrict__ bias,
    const float* __restrict__ h_in, const float* __restrict__ c_in,
    float* __restrict__ h_out, float* __restrict__ c_out) {
  const int tx = threadIdx.x & 15, ty = threadIdx.x >> 4;
  const int x0 = (blockIdx.x & 3) * 16 + tx;
  const int y0 = (blockIdx.x >> 2) * 16 + ty;
  const int ft = blockIdx.y;
  const int b = blockIdx.z;
  const int pix = y0 * 64 + x0;

  const bool vym = y0 > 0, vyp = y0 < 63, vxm = x0 > 0, vxp = x0 < 63;
  bool val[9] = {vym && vxm, vym, vym && vxp,
                 vxm,        true, vxp,
                 vyp && vxm, vyp, vyp && vxp};
  int off[9];
#pragma unroll
  for (int dy = 0; dy < 3; ++dy) {
#pragma unroll
    for (int dx = 0; dx < 3; ++dx) {
      int yy = y0 + dy - 1; yy = yy < 0 ? 0 : (yy > 63 ? 63 : yy);
      int xx = x0 + dx - 1; xx = xx < 0 ? 0 : (xx > 63 ? 63 : xx);
      off[dy * 3 + dx] = yy * 64 + xx;
    }
  }

  float acc[8][4];
#pragma unroll
  for (int j = 0; j < 8; ++j)
#pragma unroll
    for (int g = 0; g < 4; ++g) acc[j][g] = bias[g * 64 + ft * 8 + j];

  if constexpr (E > 0) {
    const float* eb = ext + (size_t)b * (size_t)extBS;
#pragma unroll 1
    for (int c = 0; c < E; ++c)
      accum_channel(eb + c * HW, off, val, Wext + (c * 8 + ft) * 288, acc);
  }
  if constexpr (!SKIP_H) {
    const float* hb = h_in + b * NF * HW;
#pragma unroll 1
    for (int c = 0; c < NF; ++c)
      accum_channel(hb + c * HW, off, val, Wh + (c * 8 + ft) * 288, acc);
  }

  const int base = (b * NF + ft * 8) * HW + pix;
#pragma unroll
  for (int j = 0; j < 8; ++j) {
    float i_ = fsig(acc[j][0]);
    float f_ = fsig(acc[j][1]);
    float o_ = fsig(acc[j][2]);
    float g_ = ftanh(acc[j][3]);
    float cp = c_in[base + j * HW];
    float cn = fmaf(f_, cp, i_ * g_);
    float hn = o_ * ftanh(cn);
    c_out[base + j * HW] = cn;
    h_out[base + j * HW] = hn;
  }
}

// head: y[b,t,0,:,:] = b_cnn + sum_f conv3x3(h[b,f], Wcnn[0,f,0])  (FLOAT out)
__global__ __launch_bounds__(256) void head_conv_k(
    const float* __restrict__ h, const float* __restrict__ wc,
    const float* __restrict__ bc, float* __restrict__ yout, int t) {
  const int tid = blockIdx.x * 256 + threadIdx.x;  // 0..131071
  const int pix = tid & 4095;
  const int b = tid >> 12;
  const int x0 = pix & 63, y0 = pix >> 6;
  const bool vym = y0 > 0, vyp = y0 < 63, vxm = x0 > 0, vxp = x0 < 63;
  bool val[9] = {vym && vxm, vym, vym && vxp,
                 vxm,        true, vxp,
                 vyp && vxm, vyp, vyp && vxp};
  int off[9];
#pragma unroll
  for (int dy = 0; dy < 3; ++dy) {
#pragma unroll
    for (int dx = 0; dx < 3; ++dx) {
      int yy = y0 + dy - 1; yy = yy < 0 ? 0 : (yy > 63 ? 63 : yy);
      int xx = x0 + dx - 1; xx = xx < 0 ? 0 : (xx > 63 ? 63 : xx);
      off[dy * 3 + dx] = yy * 64 + xx;
    }
  }
  float acc = bc[0];
  const float* hb = h + b * NF * HW;
#pragma unroll 1
  for (int f = 0; f < NF; ++f) {
    const float* hp = hb + f * HW;
    const float* w = wc + f * 9;
#pragma unroll
    for (int k = 0; k < 9; ++k) acc = fmaf(w[k], val[k] ? hp[off[k]] : 0.f, acc);
  }
  yout[(b * 12 + t) * HW + pix] = acc;
}

// final encoder h -> output 1 (FLOAT)
__global__ __launch_bounds__(256) void ev_copy_k(const float* __restrict__ h,
                                                 float* __restrict__ outp) {
  const int i = blockIdx.x * 256 + threadIdx.x;
  outp[i] = h[i];
}

// reorder W_enc [256][65][3][3] f32 -> [c][ft][j*4+g][k] f32
__global__ __launch_bounds__(256) void reorder_enc_k(const float* __restrict__ src,
                                                     float* __restrict__ dst) {
  const int idx = blockIdx.x * 256 + threadIdx.x;
  if (idx >= 65 * 2304) return;
  const int k = idx % 9;
  const int g = (idx / 9) % 4;
  const int j = (idx / 36) % 8;
  const int ft = (idx / 288) % 8;
  const int c = idx / 2304;
  const int oc = g * 64 + ft * 8 + j;
  dst[idx] = src[(oc * 65 + c) * 9 + k];
}

// reorder W_dec [256][128][3][3]: dx = x-part (c 0..63), dsum = x-part + h-part
__global__ __launch_bounds__(256) void reorder_dec_k(const float* __restrict__ src,
                                                     float* __restrict__ dx,
                                                     float* __restrict__ dsum) {
  const int idx = blockIdx.x * 256 + threadIdx.x;
  if (idx >= 64 * 2304) return;
  const int k = idx % 9;
  const int g = (idx / 9) % 4;
  const int j = (idx / 36) % 8;
  const int ft = (idx / 288) % 8;
  const int c = idx / 2304;
  const int oc = g * 64 + ft * 8 + j;
  float wx = src[(oc * 128 + c) * 9 + k];
  float wh = src[(oc * 128 + 64 + c) * 9 + k];
  dx[idx] = wx;
  dsum[idx] = wx + wh;
}

extern "C" void kernel_launch(void* const* d_in, const int* in_sizes, int n_in,
                              void* d_out, int out_size, void* d_ws, size_t ws_size,
                              hipStream_t stream) {
  const float* x = (const float*)d_in[0];       // [32,12,1,64,64] f32
  // d_in[1] = future_step (=12, hardcoded)
  const float* W_enc = (const float*)d_in[2];   // [256,65,3,3] f32
  const float* b_enc = (const float*)d_in[3];   // [256] f32 (zeros)
  const float* W_dec = (const float*)d_in[4];   // [256,128,3,3] f32
  const float* b_dec = (const float*)d_in[5];   // [256] f32 (zeros)
  const float* W_cnn = (const float*)d_in[6];   // [1,64,1,3,3] f32
  const float* b_cnn = (const float*)d_in[7];   // [1] f32 (zero)
  float* out = (float*)d_out;                   // FLOAT32 output
  float* out_y = out;                           // 1572864 floats
  float* out_ev = out + 1572864;                // 8388608 floats

  float* ws = (float*)d_ws;
  float* h0 = ws;                     // 8388608
  float* h1 = ws + 8388608;           // 8388608
  float* cc = ws + 16777216;          // 8388608
  float* WrE = ws + 25165824;         // 149760
  float* WrDx = WrE + 149760;         // 147456
  float* WrDs = WrDx + 147456;        // 147456   (total ~102.4 MB)

  reorder_enc_k<<<(65 * 2304 + 255) / 256, 256, 0, stream>>>(W_enc, WrE);
  reorder_dec_k<<<(64 * 2304 + 255) / 256, 256, 0, stream>>>(W_dec, WrDx, WrDs);

  hipMemsetAsync(h0, 0, 8388608 * sizeof(float), stream);
  hipMemsetAsync(cc, 0, 8388608 * sizeof(float), stream);

  dim3 grid(16, 8, 32), blk(256);
  float* ha = h0;
  float* hb = h1;
  // ---- encoder: x channel (E=1, stride 12*HW per batch) + h (64ch) ----
  for (int t = 0; t < 12; ++t) {
    lstm_step_k<1, false><<<grid, blk, 0, stream>>>(
        x + t * HW, 12 * HW, WrE, WrE + 2304, b_enc, ha, cc, hb, cc);
    float* tmp = ha; ha = hb; hb = tmp;
  }
  // ha holds final encoder h -> output 1 (f32)
  ev_copy_k<<<8388608 / 256, 256, 0, stream>>>(ha, out_ev);

  hipMemsetAsync(cc, 0, 8388608 * sizeof(float), stream);

  // ---- decoder ----
  for (int t = 0; t < 12; ++t) {
    if (t == 0) {
      // comb=[ev, h0=0]: only ev-part conv (ev = final encoder h, in ha)
      lstm_step_k<64, true><<<grid, blk, 0, stream>>>(
          ha, NF * HW, WrDx, (const float*)nullptr, b_dec,
          (const float*)nullptr, cc, hb, cc);
    } else {
      // comb=[h,h]: 64-channel conv with summed weights
      lstm_step_k<0, false><<<grid, blk, 0, stream>>>(
          (const float*)nullptr, 0, (const float*)nullptr, WrDs, b_dec, ha, cc, hb, cc);
    }
    head_conv_k<<<512, 256, 0, stream>>>(hb, W_cnn, b_cnn, out_y, t);
    float* tmp = ha; ha = hb; hb = tmp;
  }
}

// Round 10
// 4144.820 us; speedup vs baseline: 4.6753x; 4.6753x over previous
//
#include <hip/hip_runtime.h>
#include <hip/hip_bf16.h>

// EncoderDecoderConvLSTM — Round 10: bf16 MFMA implicit-GEMM ConvLSTM step.
// h stored [b][4096 pix][64 ch] bf16; c [b][4096][64] f32; weights [9][256][64] bf16.
// Block = one (b, y-row): 256 oc x 64 px. Wave w owns nf slice w*16..+15 via
// m-tiles oc = g*64 + w*16 (g = gate) -> i,f,o,g of one nf live in the same
// lanes => in-register LSTM epilogue, no LDS round-trip.
// Decoder t>=1 uses presummed (Wx+Wh); t=0 uses Wx with hin = h_enc (=ev).

#define HW 4096
#define NF 64

typedef __attribute__((ext_vector_type(8))) short bf16x8;
typedef __attribute__((ext_vector_type(4))) float f32x4;

__device__ __forceinline__ float fsig(float v) {
  return __builtin_amdgcn_rcpf(1.f + __expf(-v));
}
__device__ __forceinline__ float ftanh(float v) {
  float vc = fminf(fmaxf(v, -15.f), 15.f);
  float e = __expf(2.f * vc);
  return (e - 1.f) * __builtin_amdgcn_rcpf(e + 1.f);
}
__device__ __forceinline__ float bf2f(short s) {
  union { unsigned u; float f; } a;
  a.u = ((unsigned)(unsigned short)s) << 16;
  return a.f;
}
__device__ __forceinline__ short f2bf(float f) {  // RNE, matches __float2bfloat16
  union { float f; unsigned u; } a;
  a.f = f;
  unsigned r = (a.u + 0x7fff + ((a.u >> 16) & 1)) >> 16;
  return (short)r;
}

// One fused ConvLSTM step. A = W (m=oc, k=ch), B = h (k=ch, n=pix).
// MFMA 16x16x32: A lane m=lane&15, k=quad*8+j ; B lane n=lane&15, k=quad*8+j ;
// C/D lane col=lane&15, row=quad*4+reg.
template <bool HAS_X>
__global__ __launch_bounds__(256) void lstm_mfma_k(
    const short* __restrict__ hin,   // [32][4096][64] bf16
    const short* __restrict__ W,     // [9][256][64] bf16
    const float* __restrict__ wx,    // [256][9] f32 (x-part) or null
    const float* __restrict__ xpl,   // x + t*HW (batch stride 12*HW) or null
    const float* __restrict__ bias,  // [256] f32
    const float* __restrict__ cin,   // [32][4096][64] f32
    short* __restrict__ hout,
    float* __restrict__ cout) {
  const int y = blockIdx.x;        // 0..63 row
  const int b = blockIdx.y;        // 0..31 batch
  const int lane = threadIdx.x & 63;
  const int wv = threadIdx.x >> 6; // wave 0..3 -> nf slice
  const int col = lane & 15;
  const int quad = lane >> 4;

  __shared__ float xs[3][64];
  if (HAS_X) {
    const float* xb = xpl + (size_t)b * (12 * HW);
    int tid = threadIdx.x;
    if (tid < 192) {
      int r = tid >> 6, cx = tid & 63;
      int py = y + r - 1;
      xs[r][cx] = (py >= 0 && py < 64) ? xb[py * 64 + cx] : 0.f;
    }
    __syncthreads();
  }

  f32x4 acc[4][4];  // [gate][n-tile]
#pragma unroll
  for (int g = 0; g < 4; ++g) {
    const int oc0 = g * 64 + wv * 16 + quad * 4;
#pragma unroll
    for (int nt = 0; nt < 4; ++nt)
#pragma unroll
      for (int r = 0; r < 4; ++r) acc[g][nt][r] = bias[oc0 + r];
  }

  if (HAS_X) {
#pragma unroll
    for (int nt = 0; nt < 4; ++nt) {
      const int px = nt * 16 + col;
#pragma unroll
      for (int tap = 0; tap < 9; ++tap) {
        const int pxx = px + (tap % 3) - 1;
        const float xv = (pxx >= 0 && pxx < 64) ? xs[tap / 3][pxx] : 0.f;
#pragma unroll
        for (int g = 0; g < 4; ++g) {
          const int oc0 = g * 64 + wv * 16 + quad * 4;
#pragma unroll
          for (int r = 0; r < 4; ++r)
            acc[g][nt][r] = fmaf(xv, wx[(oc0 + r) * 9 + tap], acc[g][nt][r]);
        }
      }
    }
  }

  const short* hb = hin + (size_t)b * (HW * 64);
#pragma unroll 1
  for (int tap = 0; tap < 9; ++tap) {
    const int dy = tap / 3 - 1, dxx = tap % 3 - 1;
    const int py = y + dy;
    const bool yok = (py >= 0) && (py < 64);
#pragma unroll
    for (int kc = 0; kc < 2; ++kc) {
      const int chb = kc * 32 + quad * 8;
      bf16x8 a[4];
#pragma unroll
      for (int g = 0; g < 4; ++g)
        a[g] = *reinterpret_cast<const bf16x8*>(
            W + tap * 16384 + (g * 64 + wv * 16 + col) * 64 + chb);
      bf16x8 bf[4];
#pragma unroll
      for (int nt = 0; nt < 4; ++nt) {
        const int px = nt * 16 + col + dxx;
        bf16x8 v = {0, 0, 0, 0, 0, 0, 0, 0};
        if (yok && px >= 0 && px < 64)
          v = *reinterpret_cast<const bf16x8*>(hb + (py * 64 + px) * 64 + chb);
        bf[nt] = v;
      }
#pragma unroll
      for (int g = 0; g < 4; ++g)
#pragma unroll
        for (int nt = 0; nt < 4; ++nt)
          acc[g][nt] = __builtin_amdgcn_mfma_f32_16x16x32_bf16(a[g], bf[nt],
                                                               acc[g][nt], 0, 0, 0);
    }
  }

  // in-register epilogue: lane holds i,f,o,g for nf = nf0..nf0+3 at pixel px
  const int nf0 = wv * 16 + quad * 4;
#pragma unroll
  for (int nt = 0; nt < 4; ++nt) {
    const int px = nt * 16 + col;
    const size_t pix = (size_t)b * HW + y * 64 + px;
    f32x4 cold = *reinterpret_cast<const f32x4*>(cin + pix * 64 + nf0);
    f32x4 cnew;
    short hnew[4];
#pragma unroll
    for (int r = 0; r < 4; ++r) {
      float i_ = fsig(acc[0][nt][r]);
      float f_ = fsig(acc[1][nt][r]);
      float o_ = fsig(acc[2][nt][r]);
      float g_ = ftanh(acc[3][nt][r]);
      float cn = fmaf(f_, cold[r], i_ * g_);
      cnew[r] = cn;
      hnew[r] = f2bf(o_ * ftanh(cn));
    }
    *reinterpret_cast<f32x4*>(cout + pix * 64 + nf0) = cnew;
    short4 hv = make_short4(hnew[0], hnew[1], hnew[2], hnew[3]);
    *reinterpret_cast<short4*>(hout + pix * 64 + nf0) = hv;
  }
}

// head: y[b,t,pix] = b_cnn + sum_{f,tap} wc2[tap][f] * h[pix+tap][f]
__global__ __launch_bounds__(256) void head_k(const short* __restrict__ h,
                                              const float* __restrict__ wc2,
                                              const float* __restrict__ bc,
                                              float* __restrict__ yout, int t) {
  const int tid = blockIdx.x * 256 + threadIdx.x;  // 131072 threads
  const int pix = tid & 4095;
  const int b = tid >> 12;
  const int x0 = pix & 63, y0 = pix >> 6;
  float acc = bc[0];
  const short* hb = h + (size_t)b * (HW * 64);
#pragma unroll
  for (int tap = 0; tap < 9; ++tap) {
    const int yy = y0 + tap / 3 - 1, xx = x0 + (tap % 3) - 1;
    if (yy < 0 || yy > 63 || xx < 0 || xx > 63) continue;
    const short* hp = hb + (yy * 64 + xx) * 64;
    const float* wp = wc2 + tap * 64;
#pragma unroll
    for (int f8 = 0; f8 < 8; ++f8) {
      bf16x8 v = *reinterpret_cast<const bf16x8*>(hp + f8 * 8);
#pragma unroll
      for (int j = 0; j < 8; ++j) acc = fmaf(wp[f8 * 8 + j], bf2f(v[j]), acc);
    }
  }
  yout[(size_t)(b * 12 + t) * HW + pix] = acc;
}

// encoder-vector output: transpose [b][pix][ch] bf16 -> [b][ch][pix] f32
__global__ __launch_bounds__(256) void ev_out_k(const short* __restrict__ h,
                                                float* __restrict__ out) {
  __shared__ float tl[64][65];
  const int b = blockIdx.y, pg = blockIdx.x;
  const int p0 = pg * 64;
  {
    const int pixl = threadIdx.x >> 2, c0 = (threadIdx.x & 3) * 16;
    const short* hp = h + ((size_t)b * HW + p0 + pixl) * 64 + c0;
#pragma unroll
    for (int i = 0; i < 16; ++i) tl[pixl][c0 + i] = bf2f(hp[i]);
  }
  __syncthreads();
  {
    const int ch = threadIdx.x >> 2, q0 = (threadIdx.x & 3) * 16;
    float* op = out + ((size_t)b * 64 + ch) * (size_t)HW + p0 + q0;
#pragma unroll
    for (int i = 0; i < 16; ++i) op[i] = tl[q0 + i][ch];
  }
}

// W_enc [256][65][3][3] f32 -> Wh bf16 [9][256][64] (h part) + wx f32 [256][9]
__global__ __launch_bounds__(256) void reo_enc_k(const float* __restrict__ src,
                                                 short* __restrict__ Wh,
                                                 float* __restrict__ wx) {
  const int idx = blockIdx.x * 256 + threadIdx.x;
  if (idx < 9 * 256 * 64) {
    const int tap = idx >> 14, oc = (idx >> 6) & 255, c = idx & 63;
    Wh[idx] = f2bf(src[(oc * 65 + (c + 1)) * 9 + tap]);
  }
  if (idx < 256 * 9) {
    const int oc = idx / 9, tap = idx % 9;
    wx[idx] = src[(oc * 65 + 0) * 9 + tap];
  }
}

// W_dec [256][128][3][3] f32 -> Wx bf16 [9][256][64], Wsum bf16 (x+h parts)
__global__ __launch_bounds__(256) void reo_dec_k(const float* __restrict__ src,
                                                 short* __restrict__ Wx,
                                                 short* __restrict__ Ws) {
  const int idx = blockIdx.x * 256 + threadIdx.x;
  if (idx >= 9 * 256 * 64) return;
  const int tap = idx >> 14, oc = (idx >> 6) & 255, c = idx & 63;
  const float a = src[(oc * 128 + c) * 9 + tap];
  const float b = src[(oc * 128 + 64 + c) * 9 + tap];
  Wx[idx] = f2bf(a);
  Ws[idx] = f2bf(a + b);
}

// W_cnn [64][9] f32 -> [9][64] f32
__global__ __launch_bounds__(256) void reo_cnn_k(const float* __restrict__ src,
                                                 float* __restrict__ wc2) {
  const int idx = blockIdx.x * 256 + threadIdx.x;
  if (idx >= 576) return;
  wc2[idx] = src[(idx % 64) * 9 + (idx / 64)];
}

extern "C" void kernel_launch(void* const* d_in, const int* in_sizes, int n_in,
                              void* d_out, int out_size, void* d_ws, size_t ws_size,
                              hipStream_t stream) {
  const float* x = (const float*)d_in[0];       // [32,12,1,64,64] f32
  const float* W_enc = (const float*)d_in[2];
  const float* b_enc = (const float*)d_in[3];
  const float* W_dec = (const float*)d_in[4];
  const float* b_dec = (const float*)d_in[5];
  const float* W_cnn = (const float*)d_in[6];
  const float* b_cnn = (const float*)d_in[7];
  float* out = (float*)d_out;
  float* out_y = out;                 // [32][12][4096]
  float* out_ev = out + 1572864;      // [32][64][4096]

  float* ws = (float*)d_ws;
  float* cA = ws;                                // 8388608 f
  float* cB = cA + 8388608;                      // 8388608 f
  short* hA = (short*)(cB + 8388608);            // 8388608 sh
  short* hB = hA + 8388608;                      // 8388608 sh
  short* WEh = hB + 8388608;                     // 147456 sh
  short* WDx = WEh + 147456;                     // 147456 sh
  short* WDs = WDx + 147456;                     // 147456 sh
  float* wx = (float*)(WDs + 147456);            // 2304 f
  float* wc2 = wx + 2304;                        // 576 f  (~101 MB total)

  reo_enc_k<<<(147456 + 255) / 256, 256, 0, stream>>>(W_enc, WEh, wx);
  reo_dec_k<<<(147456 + 255) / 256, 256, 0, stream>>>(W_dec, WDx, WDs);
  reo_cnn_k<<<3, 256, 0, stream>>>(W_cnn, wc2);

  hipMemsetAsync(hA, 0, 8388608 * sizeof(short), stream);
  hipMemsetAsync(cA, 0, 8388608 * sizeof(float), stream);

  dim3 grid(64, 32), blk(256);
  short *ha = hA, *hb = hB;
  float *ca = cA, *cb = cB;

  // ---- encoder ----
  for (int t = 0; t < 12; ++t) {
    lstm_mfma_k<true><<<grid, blk, 0, stream>>>(ha, WEh, wx, x + t * HW, b_enc,
                                                ca, hb, cb);
    { short* tm = ha; ha = hb; hb = tm; }
    { float* tm = ca; ca = cb; cb = tm; }
  }
  // ha = h_enc -> output 1 (transposed to [b][ch][pix] f32)
  ev_out_k<<<grid, blk, 0, stream>>>(ha, out_ev);

  // fresh zero c for decoder (cb is the dead buffer after the loop)
  hipMemsetAsync(cb, 0, 8388608 * sizeof(float), stream);
  { float* tm = ca; ca = cb; cb = tm; }  // ca = zeroed c

  // ---- decoder ----
  for (int t = 0; t < 12; ++t) {
    lstm_mfma_k<false><<<grid, blk, 0, stream>>>(
        ha, (t == 0) ? WDx : WDs, nullptr, nullptr, b_dec, ca, hb, cb);
    { short* tm = ha; ha = hb; hb = tm; }
    { float* tm = ca; ca = cb; cb = tm; }
    head_k<<<512, 256, 0, stream>>>(ha, wc2, b_cnn, out_y, t);
  }
}

// Round 11
// 2962.992 us; speedup vs baseline: 6.5401x; 1.3989x over previous
//
#include <hip/hip_runtime.h>
#include <hip/hip_bf16.h>

// EncoderDecoderConvLSTM — Round 11: LDS-staged halo for B fragments.
// Round-10 was latency-bound (MfmaUtil 8.7%, VALUBusy 15%): scattered global
// 16B B-loads + border cndmask in the hot loop. Now: block stages rows
// y-1..y+1 (zero-padded, px-slot stride 66 shorts = 33 banks, ~2-way free)
// into LDS once, hot loop reads ds_read_b128. A stays global (L1-resident).
// h [b][4096][64] bf16; c f32; W [9][256][64] bf16; in-register LSTM epilogue.

#define HW 4096
#define NF 64

typedef __attribute__((ext_vector_type(8))) short bf16x8;
typedef __attribute__((ext_vector_type(4))) float f32x4;

__device__ __forceinline__ float fsig(float v) {
  return __builtin_amdgcn_rcpf(1.f + __expf(-v));
}
__device__ __forceinline__ float ftanh(float v) {
  float vc = fminf(fmaxf(v, -15.f), 15.f);
  float e = __expf(2.f * vc);
  return (e - 1.f) * __builtin_amdgcn_rcpf(e + 1.f);
}
__device__ __forceinline__ float bf2f(short s) {
  union { unsigned u; float f; } a;
  a.u = ((unsigned)(unsigned short)s) << 16;
  return a.f;
}
__device__ __forceinline__ short f2bf(float f) {  // RNE
  union { float f; unsigned u; } a;
  a.f = f;
  unsigned r = (a.u + 0x7fff + ((a.u >> 16) & 1)) >> 16;
  return (short)r;
}

// LDS halo layout: [row 0..2][px-slot 0..65][ch 0..63 + 2 pad], slot stride 66
// shorts (132 B = 33 banks), row stride 66*66 = 4356 shorts. Slot p holds
// pixel px = p-1; slots 0 and 65 are zero (x border), OOB rows zeroed.
template <bool HAS_X>
__global__ __launch_bounds__(256) void lstm_mfma_k(
    const short* __restrict__ hin,   // [32][4096][64] bf16
    const short* __restrict__ W,     // [9][256][64] bf16
    const float* __restrict__ wx,    // [256][9] f32 (x-part) or null
    const float* __restrict__ xpl,   // x + t*HW (batch stride 12*HW) or null
    const float* __restrict__ bias,  // [256] f32
    const float* __restrict__ cin,   // [32][4096][64] f32
    short* __restrict__ hout,
    float* __restrict__ cout) {
  const int y = blockIdx.x;        // 0..63 row
  const int b = blockIdx.y;        // 0..31 batch
  const int lane = threadIdx.x & 63;
  const int wv = threadIdx.x >> 6; // wave 0..3 -> nf slice
  const int col = lane & 15;
  const int quad = lane >> 4;

  __shared__ short hs[3 * 66 * 66];
  __shared__ float xs[3][64];

  const short* hb = hin + (size_t)b * (HW * 64);
  // ---- stage interior: 3 rows x 64 px x 64 ch = 1536 16B chunks ----
#pragma unroll
  for (int i = 0; i < 6; ++i) {
    const int t = threadIdx.x + i * 256;   // 0..1535
    const int r = t >> 9;                  // 0..2
    const int c = t & 511;                 // chunk in row
    const int px = c >> 3;                 // 0..63
    const int ch0 = (c & 7) * 8;
    const int py = y + r - 1;
    bf16x8 v = {0, 0, 0, 0, 0, 0, 0, 0};
    if (py >= 0 && py < 64)
      v = *reinterpret_cast<const bf16x8*>(hb + ((py * 64 + px) * 64) + ch0);
    *reinterpret_cast<bf16x8*>(&hs[(r * 66 + px + 1) * 66 + ch0]) = v;
  }
  // ---- zero x-border slots (3 rows x 2 slots x 8 chunks = 48) ----
  if (threadIdx.x < 48) {
    const int r = threadIdx.x >> 4;
    const int slot = ((threadIdx.x >> 3) & 1) * 65;
    const int ch0 = (threadIdx.x & 7) * 8;
    bf16x8 z = {0, 0, 0, 0, 0, 0, 0, 0};
    *reinterpret_cast<bf16x8*>(&hs[(r * 66 + slot) * 66 + ch0]) = z;
  }
  if (HAS_X) {
    if (threadIdx.x < 192) {
      const float* xb = xpl + (size_t)b * (12 * HW);
      const int r = threadIdx.x >> 6, cx = threadIdx.x & 63;
      const int py = y + r - 1;
      xs[r][cx] = (py >= 0 && py < 64) ? xb[py * 64 + cx] : 0.f;
    }
  }
  __syncthreads();

  f32x4 acc[4][4];  // [gate][n-tile]
#pragma unroll
  for (int g = 0; g < 4; ++g) {
    const int oc0 = g * 64 + wv * 16 + quad * 4;
#pragma unroll
    for (int nt = 0; nt < 4; ++nt)
#pragma unroll
      for (int r = 0; r < 4; ++r) acc[g][nt][r] = bias[oc0 + r];
  }

  if (HAS_X) {
#pragma unroll
    for (int nt = 0; nt < 4; ++nt) {
      const int px = nt * 16 + col;
#pragma unroll
      for (int tap = 0; tap < 9; ++tap) {
        const int pxx = px + (tap % 3) - 1;
        const float xv = (pxx >= 0 && pxx < 64) ? xs[tap / 3][pxx] : 0.f;
#pragma unroll
        for (int g = 0; g < 4; ++g) {
          const int oc0 = g * 64 + wv * 16 + quad * 4;
#pragma unroll
          for (int r = 0; r < 4; ++r)
            acc[g][nt][r] = fmaf(xv, wx[(oc0 + r) * 9 + tap], acc[g][nt][r]);
        }
      }
    }
  }

  // ---- main conv loop: A from global (L1), B from LDS ----
#pragma unroll 3
  for (int tap = 0; tap < 9; ++tap) {
    const int r = tap / 3;
    const int dxx = tap % 3 - 1;
    const int hbase = r * 4356 + (col + dxx + 1) * 66;
#pragma unroll
    for (int kc = 0; kc < 2; ++kc) {
      const int chb = kc * 32 + quad * 8;
      bf16x8 a[4];
#pragma unroll
      for (int g = 0; g < 4; ++g)
        a[g] = *reinterpret_cast<const bf16x8*>(
            W + tap * 16384 + (g * 64 + wv * 16 + col) * 64 + chb);
      bf16x8 bfr[4];
#pragma unroll
      for (int nt = 0; nt < 4; ++nt)
        bfr[nt] = *reinterpret_cast<const bf16x8*>(&hs[hbase + nt * 1056 + chb]);
#pragma unroll
      for (int g = 0; g < 4; ++g)
#pragma unroll
        for (int nt = 0; nt < 4; ++nt)
          acc[g][nt] = __builtin_amdgcn_mfma_f32_16x16x32_bf16(a[g], bfr[nt],
                                                               acc[g][nt], 0, 0, 0);
    }
  }

  // ---- in-register epilogue ----
  const int nf0 = wv * 16 + quad * 4;
#pragma unroll
  for (int nt = 0; nt < 4; ++nt) {
    const int px = nt * 16 + col;
    const size_t pix = (size_t)b * HW + y * 64 + px;
    f32x4 cold = *reinterpret_cast<const f32x4*>(cin + pix * 64 + nf0);
    f32x4 cnew;
    short hnew[4];
#pragma unroll
    for (int r = 0; r < 4; ++r) {
      float i_ = fsig(acc[0][nt][r]);
      float f_ = fsig(acc[1][nt][r]);
      float o_ = fsig(acc[2][nt][r]);
      float g_ = ftanh(acc[3][nt][r]);
      float cn = fmaf(f_, cold[r], i_ * g_);
      cnew[r] = cn;
      hnew[r] = f2bf(o_ * ftanh(cn));
    }
    *reinterpret_cast<f32x4*>(cout + pix * 64 + nf0) = cnew;
    short4 hv = make_short4(hnew[0], hnew[1], hnew[2], hnew[3]);
    *reinterpret_cast<short4*>(hout + pix * 64 + nf0) = hv;
  }
}

// head: y[b,t,pix] = b_cnn + sum_{f,tap} wc2[tap][f] * h[pix+tap][f]
__global__ __launch_bounds__(256) void head_k(const short* __restrict__ h,
                                              const float* __restrict__ wc2,
                                              const float* __restrict__ bc,
                                              float* __restrict__ yout, int t) {
  const int tid = blockIdx.x * 256 + threadIdx.x;  // 131072 threads
  const int pix = tid & 4095;
  const int b = tid >> 12;
  const int x0 = pix & 63, y0 = pix >> 6;
  float acc = bc[0];
  const short* hb = h + (size_t)b * (HW * 64);
#pragma unroll
  for (int tap = 0; tap < 9; ++tap) {
    const int yy = y0 + tap / 3 - 1, xx = x0 + (tap % 3) - 1;
    if (yy < 0 || yy > 63 || xx < 0 || xx > 63) continue;
    const short* hp = hb + (yy * 64 + xx) * 64;
    const float* wp = wc2 + tap * 64;
#pragma unroll
    for (int f8 = 0; f8 < 8; ++f8) {
      bf16x8 v = *reinterpret_cast<const bf16x8*>(hp + f8 * 8);
#pragma unroll
      for (int j = 0; j < 8; ++j) acc = fmaf(wp[f8 * 8 + j], bf2f(v[j]), acc);
    }
  }
  yout[(size_t)(b * 12 + t) * HW + pix] = acc;
}

// encoder-vector output: transpose [b][pix][ch] bf16 -> [b][ch][pix] f32
__global__ __launch_bounds__(256) void ev_out_k(const short* __restrict__ h,
                                                float* __restrict__ out) {
  __shared__ float tl[64][65];
  const int b = blockIdx.y, pg = blockIdx.x;
  const int p0 = pg * 64;
  {
    const int pixl = threadIdx.x >> 2, c0 = (threadIdx.x & 3) * 16;
    const short* hp = h + ((size_t)b * HW + p0 + pixl) * 64 + c0;
#pragma unroll
    for (int i = 0; i < 16; ++i) tl[pixl][c0 + i] = bf2f(hp[i]);
  }
  __syncthreads();
  {
    const int ch = threadIdx.x >> 2, q0 = (threadIdx.x & 3) * 16;
    float* op = out + ((size_t)b * 64 + ch) * (size_t)HW + p0 + q0;
#pragma unroll
    for (int i = 0; i < 16; ++i) op[i] = tl[q0 + i][ch];
  }
}

// W_enc [256][65][3][3] f32 -> Wh bf16 [9][256][64] (h part) + wx f32 [256][9]
__global__ __launch_bounds__(256) void reo_enc_k(const float* __restrict__ src,
                                                 short* __restrict__ Wh,
                                                 float* __restrict__ wx) {
  const int idx = blockIdx.x * 256 + threadIdx.x;
  if (idx < 9 * 256 * 64) {
    const int tap = idx >> 14, oc = (idx >> 6) & 255, c = idx & 63;
    Wh[idx] = f2bf(src[(oc * 65 + (c + 1)) * 9 + tap]);
  }
  if (idx < 256 * 9) {
    const int oc = idx / 9, tap = idx % 9;
    wx[idx] = src[(oc * 65 + 0) * 9 + tap];
  }
}

// W_dec [256][128][3][3] f32 -> Wx bf16 [9][256][64], Wsum bf16 (x+h parts)
__global__ __launch_bounds__(256) void reo_dec_k(const float* __restrict__ src,
                                                 short* __restrict__ Wx,
                                                 short* __restrict__ Ws) {
  const int idx = blockIdx.x * 256 + threadIdx.x;
  if (idx >= 9 * 256 * 64) return;
  const int tap = idx >> 14, oc = (idx >> 6) & 255, c = idx & 63;
  const float a = src[(oc * 128 + c) * 9 + tap];
  const float b = src[(oc * 128 + 64 + c) * 9 + tap];
  Wx[idx] = f2bf(a);
  Ws[idx] = f2bf(a + b);
}

// W_cnn [64][9] f32 -> [9][64] f32
__global__ __launch_bounds__(256) void reo_cnn_k(const float* __restrict__ src,
                                                 float* __restrict__ wc2) {
  const int idx = blockIdx.x * 256 + threadIdx.x;
  if (idx >= 576) return;
  wc2[idx] = src[(idx % 64) * 9 + (idx / 64)];
}

extern "C" void kernel_launch(void* const* d_in, const int* in_sizes, int n_in,
                              void* d_out, int out_size, void* d_ws, size_t ws_size,
                              hipStream_t stream) {
  const float* x = (const float*)d_in[0];       // [32,12,1,64,64] f32
  const float* W_enc = (const float*)d_in[2];
  const float* b_enc = (const float*)d_in[3];
  const float* W_dec = (const float*)d_in[4];
  const float* b_dec = (const float*)d_in[5];
  const float* W_cnn = (const float*)d_in[6];
  const float* b_cnn = (const float*)d_in[7];
  float* out = (float*)d_out;
  float* out_y = out;                 // [32][12][4096]
  float* out_ev = out + 1572864;      // [32][64][4096]

  float* ws = (float*)d_ws;
  float* cA = ws;                                // 8388608 f
  float* cB = cA + 8388608;                      // 8388608 f
  short* hA = (short*)(cB + 8388608);            // 8388608 sh
  short* hB = hA + 8388608;                      // 8388608 sh
  short* WEh = hB + 8388608;                     // 147456 sh
  short* WDx = WEh + 147456;                     // 147456 sh
  short* WDs = WDx + 147456;                     // 147456 sh
  float* wx = (float*)(WDs + 147456);            // 2304 f
  float* wc2 = wx + 2304;                        // 576 f  (~101 MB total)

  reo_enc_k<<<(147456 + 255) / 256, 256, 0, stream>>>(W_enc, WEh, wx);
  reo_dec_k<<<(147456 + 255) / 256, 256, 0, stream>>>(W_dec, WDx, WDs);
  reo_cnn_k<<<3, 256, 0, stream>>>(W_cnn, wc2);

  hipMemsetAsync(hA, 0, 8388608 * sizeof(short), stream);
  hipMemsetAsync(cA, 0, 8388608 * sizeof(float), stream);

  dim3 grid(64, 32), blk(256);
  short *ha = hA, *hb = hB;
  float *ca = cA, *cb = cB;

  // ---- encoder ----
  for (int t = 0; t < 12; ++t) {
    lstm_mfma_k<true><<<grid, blk, 0, stream>>>(ha, WEh, wx, x + t * HW, b_enc,
                                                ca, hb, cb);
    { short* tm = ha; ha = hb; hb = tm; }
    { float* tm = ca; ca = cb; cb = tm; }
  }
  // ha = h_enc -> output 1 (transposed to [b][ch][pix] f32)
  ev_out_k<<<grid, blk, 0, stream>>>(ha, out_ev);

  // fresh zero c for decoder
  hipMemsetAsync(cb, 0, 8388608 * sizeof(float), stream);
  { float* tm = ca; ca = cb; cb = tm; }  // ca = zeroed c

  // ---- decoder ----
  for (int t = 0; t < 12; ++t) {
    lstm_mfma_k<false><<<grid, blk, 0, stream>>>(
        ha, (t == 0) ? WDx : WDs, nullptr, nullptr, b_dec, ca, hb, cb);
    { short* tm = ha; ha = hb; hb = tm; }
    { float* tm = ca; ca = cb; cb = tm; }
    head_k<<<512, 256, 0, stream>>>(ha, wc2, b_cnn, out_y, t);
  }
}